// Round 9
// baseline (94.883 us; speedup 1.0000x reference)
//
#include <hip/hip_runtime.h>
#include <stdint.h>

#define NCLS 14
#define BATCH 2
#define NUM_BINS (BATCH * NCLS)   // 28
#define SLOT_STRIDE 32            // pad 28 bins -> 32 (128B line per block)
#define KSPREAD 64                // fallback path spread

// slot path ws layout: float fsum[grid*32] | int fcnt[grid*32]
// fallback ws layout:  float fsum[28*64]   | int fcnt[28*64]

__device__ __forceinline__ void kd9_compute(
        const float* __restrict__ S, const float* __restrict__ T,
        const int* __restrict__ gt, int N,
        float* lsum, int* lcnt, int* b_out) {
    if (threadIdx.x < NUM_BINS) { lsum[threadIdx.x] = 0.0f; lcnt[threadIdx.x] = 0; }
    __syncthreads();

    const int gid = blockIdx.x * blockDim.x + threadIdx.x;
    const int v0 = gid * 4;            // 4 voxels/thread; block covers 1024 voxels
    const int b = (v0 >= N) ? 1 : 0;   // N % 1024 == 0: block never straddles
    const int n = v0 - b * N;
    *b_out = b;

    const float4* Sp = reinterpret_cast<const float4*>(S + (size_t)(b * NCLS) * N + n);
    const float4* Tp = reinterpret_cast<const float4*>(T + (size_t)(b * NCLS) * N + n);
    const int quartN = N >> 2;

    float4 sv[NCLS], tv[NCLS];
#pragma unroll
    for (int c = 0; c < NCLS; ++c) sv[c] = Sp[c * quartN];
#pragma unroll
    for (int c = 0; c < NCLS; ++c) tv[c] = Tp[c * quartN];
    int4 g = *reinterpret_cast<const int4*>(gt + v0);

    float Zs[4] = {0,0,0,0}, Zt[4] = {0,0,0,0};
    float At[4] = {0,0,0,0}, As[4] = {0,0,0,0};
#pragma unroll
    for (int c = 0; c < NCLS; ++c) {
        float s[4] = {sv[c].x, sv[c].y, sv[c].z, sv[c].w};
        float t[4] = {tv[c].x, tv[c].y, tv[c].z, tv[c].w};
#pragma unroll
        for (int v = 0; v < 4; ++v) {
            float et = __expf(t[v]);
            Zt[v] += et;
            At[v] = fmaf(et, t[v], At[v]);
            As[v] = fmaf(et, s[v], As[v]);
            Zs[v] += __expf(s[v]);
        }
    }

    int cls[4] = {g.x, g.y, g.z, g.w};
#pragma unroll
    for (int v = 0; v < 4; ++v) {
        // kl = sum_c q(logq - logp) = (At - As)/Zt - log(Zt) + log(Zs)
        float kl = (At[v] - As[v]) / Zt[v] - __logf(Zt[v]) + __logf(Zs[v]);
        int c = min(max(cls[v], 0), NCLS - 1);
        atomicAdd(&lsum[b * NCLS + c], kl);
        atomicAdd(&lcnt[b * NCLS + c], 1);
    }
    __syncthreads();
}

// ---- slot path: per-block private stores, no atomics, no pre-zero ----
__global__ __launch_bounds__(256) void kd9_kl_slots(
        const float* __restrict__ S, const float* __restrict__ T,
        const int* __restrict__ gt,
        float* __restrict__ fsum, int* __restrict__ fcnt, int N) {
    __shared__ float lsum[NUM_BINS];
    __shared__ int lcnt[NUM_BINS];
    int b;
    kd9_compute(S, T, gt, N, lsum, lcnt, &b);
    if (threadIdx.x < NUM_BINS) {
        fsum[blockIdx.x * SLOT_STRIDE + threadIdx.x] = lsum[threadIdx.x];
        fcnt[blockIdx.x * SLOT_STRIDE + threadIdx.x] = lcnt[threadIdx.x];
    }
}

__global__ __launch_bounds__(256) void kd9_final_slots(
        const float* __restrict__ fsum, const int* __restrict__ fcnt,
        float* __restrict__ out, int grid) {
    __shared__ float wsum[4];
    __shared__ int wcnt[4];
    const int tid = threadIdx.x;
    const int wave = tid >> 6, lane = tid & 63;
    float loss = 0.0f;
    for (int bin = 0; bin < NUM_BINS; ++bin) {
        float s = 0.0f; int n = 0;
        for (int i = tid; i < grid; i += 256) {
            s += fsum[i * SLOT_STRIDE + bin];
            n += fcnt[i * SLOT_STRIDE + bin];
        }
#pragma unroll
        for (int off = 32; off >= 1; off >>= 1) {
            s += __shfl_down(s, off);
            n += __shfl_down(n, off);
        }
        if (lane == 0) { wsum[wave] = s; wcnt[wave] = n; }
        __syncthreads();
        if (tid == 0) {
            float ts = wsum[0] + wsum[1] + wsum[2] + wsum[3];
            int tn = wcnt[0] + wcnt[1] + wcnt[2] + wcnt[3];
            int cls = bin % NCLS;
            if (cls != 0 && tn > 0) loss += ts / ((float)NCLS * (float)tn);
        }
        __syncthreads();
    }
    if (tid == 0) out[0] = loss;   // TAU^2 = 1, LOSS_WEIGHT = 1
}

// ---- fallback path (round-8 proven): 64-way-spread atomics ----
__global__ void kd9_zero(float* __restrict__ fsum, int* __restrict__ fcnt) {
    int i = blockIdx.x * blockDim.x + threadIdx.x;
    fsum[i] = 0.0f;
    fcnt[i] = 0;
}

__global__ __launch_bounds__(256) void kd9_kl_atomic(
        const float* __restrict__ S, const float* __restrict__ T,
        const int* __restrict__ gt,
        float* __restrict__ fsum, int* __restrict__ fcnt, int N) {
    __shared__ float lsum[NUM_BINS];
    __shared__ int lcnt[NUM_BINS];
    int b;
    kd9_compute(S, T, gt, N, lsum, lcnt, &b);
    if (threadIdx.x < NUM_BINS) {
        const int slot = blockIdx.x & (KSPREAD - 1);
        atomicAdd(&fsum[threadIdx.x * KSPREAD + slot], lsum[threadIdx.x]);
        atomicAdd(&fcnt[threadIdx.x * KSPREAD + slot], lcnt[threadIdx.x]);
    }
}

__global__ void kd9_final_atomic(const float* __restrict__ fsum,
                                 const int* __restrict__ fcnt,
                                 float* __restrict__ out) {
    __shared__ float terms[64];
    const int t = threadIdx.x;
    float term = 0.0f;
    if (t < NUM_BINS) {
        float s = 0.0f; int n = 0;
#pragma unroll
        for (int i = 0; i < KSPREAD; ++i) {
            s += fsum[t * KSPREAD + i];
            n += fcnt[t * KSPREAD + i];
        }
        const int cls = t % NCLS;
        if (cls != 0 && n > 0) term = s / ((float)NCLS * (float)n);
    }
    terms[t] = term;
    __syncthreads();
    if (t == 0) {
        float loss = 0.0f;
#pragma unroll
        for (int i = 0; i < 64; ++i) loss += terms[i];
        out[0] = loss;
    }
}

extern "C" void kernel_launch(void* const* d_in, const int* in_sizes, int n_in,
                              void* d_out, int out_size, void* d_ws, size_t ws_size,
                              hipStream_t stream) {
    const float* S = (const float*)d_in[0];
    const float* T = (const float*)d_in[1];
    const int* gt = (const int*)d_in[2];
    float* out = (float*)d_out;

    const int totalVox = in_sizes[2];       // 1,769,472 = 1728 * 1024
    const int N = totalVox / BATCH;         // 884,736 (divisible by 1024)

    const int block = 256;
    const int grid = totalVox / (block * 4);  // 1728 blocks, 4 voxels/thread

    const size_t slot_bytes = (size_t)grid * SLOT_STRIDE * (sizeof(float) + sizeof(int));
    if (ws_size >= slot_bytes) {
        float* fsum = (float*)d_ws;
        int* fcnt = (int*)((char*)d_ws + (size_t)grid * SLOT_STRIDE * sizeof(float));
        kd9_kl_slots<<<grid, block, 0, stream>>>(S, T, gt, fsum, fcnt, N);
        kd9_final_slots<<<1, 256, 0, stream>>>(fsum, fcnt, out, grid);
    } else {
        float* fsum = (float*)d_ws;
        int* fcnt = (int*)((char*)d_ws + NUM_BINS * KSPREAD * sizeof(float));
        kd9_zero<<<(NUM_BINS * KSPREAD) / 256, 256, 0, stream>>>(fsum, fcnt);
        kd9_kl_atomic<<<grid, block, 0, stream>>>(S, T, gt, fsum, fcnt, N);
        kd9_final_atomic<<<1, 64, 0, stream>>>(fsum, fcnt, out);
    }
}

// Round 10
// 67.804 us; speedup vs baseline: 1.3994x; 1.3994x over previous
//
#include <hip/hip_runtime.h>
#include <stdint.h>

#define NCLS 14
#define BATCH 2
#define NUM_BINS (BATCH * NCLS)   // 28
#define KSPREAD 64                // fallback path spread

// slot path ws layout (bin-major / transposed):
//   float fsum[NUM_BINS * grid] | int fcnt[NUM_BINS * grid]   (387 KB @ grid=1728)
// fallback ws layout: float fsum[28*64] | int fcnt[28*64]

__device__ __forceinline__ void kd10_compute(
        const float* __restrict__ S, const float* __restrict__ T,
        const int* __restrict__ gt, int N,
        float* lsum, int* lcnt) {
    if (threadIdx.x < NUM_BINS) { lsum[threadIdx.x] = 0.0f; lcnt[threadIdx.x] = 0; }
    __syncthreads();

    const int gid = blockIdx.x * blockDim.x + threadIdx.x;
    const int v0 = gid * 4;            // 4 voxels/thread; block covers 1024 voxels
    const int b = (v0 >= N) ? 1 : 0;   // N % 1024 == 0: block never straddles
    const int n = v0 - b * N;

    const float4* Sp = reinterpret_cast<const float4*>(S + (size_t)(b * NCLS) * N + n);
    const float4* Tp = reinterpret_cast<const float4*>(T + (size_t)(b * NCLS) * N + n);
    const int quartN = N >> 2;

    float4 sv[NCLS], tv[NCLS];
#pragma unroll
    for (int c = 0; c < NCLS; ++c) sv[c] = Sp[c * quartN];
#pragma unroll
    for (int c = 0; c < NCLS; ++c) tv[c] = Tp[c * quartN];
    int4 g = *reinterpret_cast<const int4*>(gt + v0);

    float Zs[4] = {0,0,0,0}, Zt[4] = {0,0,0,0};
    float At[4] = {0,0,0,0}, As[4] = {0,0,0,0};
#pragma unroll
    for (int c = 0; c < NCLS; ++c) {
        float s[4] = {sv[c].x, sv[c].y, sv[c].z, sv[c].w};
        float t[4] = {tv[c].x, tv[c].y, tv[c].z, tv[c].w};
#pragma unroll
        for (int v = 0; v < 4; ++v) {
            float et = __expf(t[v]);
            Zt[v] += et;
            At[v] = fmaf(et, t[v], At[v]);
            As[v] = fmaf(et, s[v], As[v]);
            Zs[v] += __expf(s[v]);
        }
    }

    int cls[4] = {g.x, g.y, g.z, g.w};
#pragma unroll
    for (int v = 0; v < 4; ++v) {
        // kl = sum_c q(logq - logp) = (At - As)/Zt - log(Zt) + log(Zs)
        float kl = (At[v] - As[v]) / Zt[v] - __logf(Zt[v]) + __logf(Zs[v]);
        int c = min(max(cls[v], 0), NCLS - 1);
        atomicAdd(&lsum[b * NCLS + c], kl);
        atomicAdd(&lcnt[b * NCLS + c], 1);
    }
    __syncthreads();
}

// ---- slot path: per-block private stores (bin-major), no atomics, no zero ----
__global__ __launch_bounds__(256) void kd10_kl_slots(
        const float* __restrict__ S, const float* __restrict__ T,
        const int* __restrict__ gt,
        float* __restrict__ fsum, int* __restrict__ fcnt, int N, int grid) {
    __shared__ float lsum[NUM_BINS];
    __shared__ int lcnt[NUM_BINS];
    kd10_compute(S, T, gt, N, lsum, lcnt);
    if (threadIdx.x < NUM_BINS) {
        fsum[(size_t)threadIdx.x * grid + blockIdx.x] = lsum[threadIdx.x];
        fcnt[(size_t)threadIdx.x * grid + blockIdx.x] = lcnt[threadIdx.x];
    }
}

// One 1024-thread block; 56 wave-tasks (28 bins x {sum,count}),
// each task reduces `grid` CONTIGUOUS elements (coalesced, 27 loads/lane).
__global__ __launch_bounds__(1024) void kd10_final_slots(
        const float* __restrict__ fsum, const int* __restrict__ fcnt,
        float* __restrict__ out, int grid) {
    __shared__ float res[2 * NUM_BINS];
    const int tid = threadIdx.x;
    const int w = tid >> 6, lane = tid & 63;

    for (int t = w; t < 2 * NUM_BINS; t += 16) {
        const int bin = t % NUM_BINS;
        const int kind = t / NUM_BINS;   // 0 = sum, 1 = count
        float acc = 0.0f;
        if (kind == 0) {
            const float* p = fsum + (size_t)bin * grid;
            for (int i = lane; i < grid; i += 64) acc += p[i];
        } else {
            const int* p = fcnt + (size_t)bin * grid;
            int n = 0;
            for (int i = lane; i < grid; i += 64) n += p[i];
            acc = (float)n;   // counts < 2^24: exact in float
        }
#pragma unroll
        for (int off = 32; off >= 1; off >>= 1) acc += __shfl_down(acc, off);
        if (lane == 0) res[t] = acc;
    }
    __syncthreads();
    if (tid == 0) {
        float loss = 0.0f;
        for (int bin = 0; bin < NUM_BINS; ++bin) {
            const int cls = bin % NCLS;
            const float s = res[bin];
            const float n = res[bin + NUM_BINS];
            if (cls != 0 && n > 0.0f) loss += s / ((float)NCLS * n);
        }
        out[0] = loss;   // TAU^2 = 1, LOSS_WEIGHT = 1
    }
}

// ---- fallback path (round-8 proven): 64-way-spread atomics ----
__global__ void kd10_zero(float* __restrict__ fsum, int* __restrict__ fcnt) {
    int i = blockIdx.x * blockDim.x + threadIdx.x;
    fsum[i] = 0.0f;
    fcnt[i] = 0;
}

__global__ __launch_bounds__(256) void kd10_kl_atomic(
        const float* __restrict__ S, const float* __restrict__ T,
        const int* __restrict__ gt,
        float* __restrict__ fsum, int* __restrict__ fcnt, int N) {
    __shared__ float lsum[NUM_BINS];
    __shared__ int lcnt[NUM_BINS];
    kd10_compute(S, T, gt, N, lsum, lcnt);
    if (threadIdx.x < NUM_BINS) {
        const int slot = blockIdx.x & (KSPREAD - 1);
        atomicAdd(&fsum[threadIdx.x * KSPREAD + slot], lsum[threadIdx.x]);
        atomicAdd(&fcnt[threadIdx.x * KSPREAD + slot], lcnt[threadIdx.x]);
    }
}

__global__ void kd10_final_atomic(const float* __restrict__ fsum,
                                  const int* __restrict__ fcnt,
                                  float* __restrict__ out) {
    __shared__ float terms[64];
    const int t = threadIdx.x;
    float term = 0.0f;
    if (t < NUM_BINS) {
        float s = 0.0f; int n = 0;
#pragma unroll
        for (int i = 0; i < KSPREAD; ++i) {
            s += fsum[t * KSPREAD + i];
            n += fcnt[t * KSPREAD + i];
        }
        const int cls = t % NCLS;
        if (cls != 0 && n > 0) term = s / ((float)NCLS * (float)n);
    }
    terms[t] = term;
    __syncthreads();
    if (t == 0) {
        float loss = 0.0f;
#pragma unroll
        for (int i = 0; i < 64; ++i) loss += terms[i];
        out[0] = loss;
    }
}

extern "C" void kernel_launch(void* const* d_in, const int* in_sizes, int n_in,
                              void* d_out, int out_size, void* d_ws, size_t ws_size,
                              hipStream_t stream) {
    const float* S = (const float*)d_in[0];
    const float* T = (const float*)d_in[1];
    const int* gt = (const int*)d_in[2];
    float* out = (float*)d_out;

    const int totalVox = in_sizes[2];       // 1,769,472 = 1728 * 1024
    const int N = totalVox / BATCH;         // 884,736 (divisible by 1024)

    const int block = 256;
    const int grid = totalVox / (block * 4);  // 1728 blocks, 4 voxels/thread

    const size_t slot_bytes = (size_t)NUM_BINS * grid * (sizeof(float) + sizeof(int));
    if (ws_size >= slot_bytes) {
        float* fsum = (float*)d_ws;
        int* fcnt = (int*)((char*)d_ws + (size_t)NUM_BINS * grid * sizeof(float));
        kd10_kl_slots<<<grid, block, 0, stream>>>(S, T, gt, fsum, fcnt, N, grid);
        kd10_final_slots<<<1, 1024, 0, stream>>>(fsum, fcnt, out, grid);
    } else {
        float* fsum = (float*)d_ws;
        int* fcnt = (int*)((char*)d_ws + NUM_BINS * KSPREAD * sizeof(float));
        kd10_zero<<<(NUM_BINS * KSPREAD) / 256, 256, 0, stream>>>(fsum, fcnt);
        kd10_kl_atomic<<<grid, block, 0, stream>>>(S, T, gt, fsum, fcnt, N);
        kd10_final_atomic<<<1, 64, 0, stream>>>(fsum, fcnt, out);
    }
}

// Round 12
// 44.235 us; speedup vs baseline: 2.1449x; 1.5328x over previous
//
#include <hip/hip_runtime.h>
#include <stdint.h>

#define NCLS 14
#define BATCH 2
#define NUM_BINS (BATCH * NCLS)   // 28
#define KSPREAD 64                // per-bin atomic spread factor

// d_ws layout: float fsum[NUM_BINS*KSPREAD] | int fcnt[NUM_BINS*KSPREAD]

__global__ void kd12_zero(float* __restrict__ fsum, int* __restrict__ fcnt) {
    int i = blockIdx.x * blockDim.x + threadIdx.x;   // grid covers 1792 exactly
    fsum[i] = 0.0f;
    fcnt[i] = 0;
}

__global__ __launch_bounds__(256) void kd12_kl(
        const float* __restrict__ S, const float* __restrict__ T,
        const int* __restrict__ gt,
        float* __restrict__ fsum, int* __restrict__ fcnt,
        int N /* voxels per batch image */) {
    __shared__ float lsum[NUM_BINS];
    __shared__ int lcnt[NUM_BINS];
    if (threadIdx.x < NUM_BINS) { lsum[threadIdx.x] = 0.0f; lcnt[threadIdx.x] = 0; }
    __syncthreads();

    // b from blockIdx only -> block-uniform -> SGPR channel bases (saddr form).
    // Block covers 1024 voxels; N % 1024 == 0 so no batch straddle.
    const int b = ((unsigned)blockIdx.x * 1024u >= (unsigned)N) ? 1 : 0;
    const int gid = blockIdx.x * blockDim.x + threadIdx.x;
    const int v0 = gid * 4;                       // 4 voxels per thread
    const int n = v0 - b * N;

    const float* Sb = S + (size_t)b * NCLS * N;   // uniform (SGPR pair)
    const float* Tb = T + (size_t)b * NCLS * N;   // uniform (SGPR pair)
    const uint32_t voff = (uint32_t)n * 4u;       // per-lane byte offset

    float4 sv[NCLS], tv[NCLS];

    // ---- Force 28 independent dwordx4 loads in flight (28 KB/wave). ----
    asm volatile(
        "global_load_dwordx4 %[d0], %[vo], %[p0]\n\t"
        "global_load_dwordx4 %[d1], %[vo], %[p1]\n\t"
        "global_load_dwordx4 %[d2], %[vo], %[p2]\n\t"
        "global_load_dwordx4 %[d3], %[vo], %[p3]\n\t"
        "global_load_dwordx4 %[d4], %[vo], %[p4]\n\t"
        "global_load_dwordx4 %[d5], %[vo], %[p5]\n\t"
        "global_load_dwordx4 %[d6], %[vo], %[p6]\n\t"
        : [d0]"=v"(sv[0]), [d1]"=v"(sv[1]), [d2]"=v"(sv[2]), [d3]"=v"(sv[3]),
          [d4]"=v"(sv[4]), [d5]"=v"(sv[5]), [d6]"=v"(sv[6])
        : [vo]"v"(voff),
          [p0]"s"(Sb + 0*(size_t)N), [p1]"s"(Sb + 1*(size_t)N),
          [p2]"s"(Sb + 2*(size_t)N), [p3]"s"(Sb + 3*(size_t)N),
          [p4]"s"(Sb + 4*(size_t)N), [p5]"s"(Sb + 5*(size_t)N),
          [p6]"s"(Sb + 6*(size_t)N));
    asm volatile(
        "global_load_dwordx4 %[d0], %[vo], %[p0]\n\t"
        "global_load_dwordx4 %[d1], %[vo], %[p1]\n\t"
        "global_load_dwordx4 %[d2], %[vo], %[p2]\n\t"
        "global_load_dwordx4 %[d3], %[vo], %[p3]\n\t"
        "global_load_dwordx4 %[d4], %[vo], %[p4]\n\t"
        "global_load_dwordx4 %[d5], %[vo], %[p5]\n\t"
        "global_load_dwordx4 %[d6], %[vo], %[p6]\n\t"
        : [d0]"=v"(sv[7]), [d1]"=v"(sv[8]), [d2]"=v"(sv[9]), [d3]"=v"(sv[10]),
          [d4]"=v"(sv[11]), [d5]"=v"(sv[12]), [d6]"=v"(sv[13])
        : [vo]"v"(voff),
          [p0]"s"(Sb + 7*(size_t)N), [p1]"s"(Sb + 8*(size_t)N),
          [p2]"s"(Sb + 9*(size_t)N), [p3]"s"(Sb + 10*(size_t)N),
          [p4]"s"(Sb + 11*(size_t)N), [p5]"s"(Sb + 12*(size_t)N),
          [p6]"s"(Sb + 13*(size_t)N));
    asm volatile(
        "global_load_dwordx4 %[d0], %[vo], %[p0]\n\t"
        "global_load_dwordx4 %[d1], %[vo], %[p1]\n\t"
        "global_load_dwordx4 %[d2], %[vo], %[p2]\n\t"
        "global_load_dwordx4 %[d3], %[vo], %[p3]\n\t"
        "global_load_dwordx4 %[d4], %[vo], %[p4]\n\t"
        "global_load_dwordx4 %[d5], %[vo], %[p5]\n\t"
        "global_load_dwordx4 %[d6], %[vo], %[p6]\n\t"
        : [d0]"=v"(tv[0]), [d1]"=v"(tv[1]), [d2]"=v"(tv[2]), [d3]"=v"(tv[3]),
          [d4]"=v"(tv[4]), [d5]"=v"(tv[5]), [d6]"=v"(tv[6])
        : [vo]"v"(voff),
          [p0]"s"(Tb + 0*(size_t)N), [p1]"s"(Tb + 1*(size_t)N),
          [p2]"s"(Tb + 2*(size_t)N), [p3]"s"(Tb + 3*(size_t)N),
          [p4]"s"(Tb + 4*(size_t)N), [p5]"s"(Tb + 5*(size_t)N),
          [p6]"s"(Tb + 6*(size_t)N));
    asm volatile(
        "global_load_dwordx4 %[d0], %[vo], %[p0]\n\t"
        "global_load_dwordx4 %[d1], %[vo], %[p1]\n\t"
        "global_load_dwordx4 %[d2], %[vo], %[p2]\n\t"
        "global_load_dwordx4 %[d3], %[vo], %[p3]\n\t"
        "global_load_dwordx4 %[d4], %[vo], %[p4]\n\t"
        "global_load_dwordx4 %[d5], %[vo], %[p5]\n\t"
        "global_load_dwordx4 %[d6], %[vo], %[p6]\n\t"
        : [d0]"=v"(tv[7]), [d1]"=v"(tv[8]), [d2]"=v"(tv[9]), [d3]"=v"(tv[10]),
          [d4]"=v"(tv[11]), [d5]"=v"(tv[12]), [d6]"=v"(tv[13])
        : [vo]"v"(voff),
          [p0]"s"(Tb + 7*(size_t)N), [p1]"s"(Tb + 8*(size_t)N),
          [p2]"s"(Tb + 9*(size_t)N), [p3]"s"(Tb + 10*(size_t)N),
          [p4]"s"(Tb + 11*(size_t)N), [p5]"s"(Tb + 12*(size_t)N),
          [p6]"s"(Tb + 13*(size_t)N));

    int4 g = *reinterpret_cast<const int4*>(gt + v0);

    // Drain all asm loads; sched_barrier(0) fences consumers below the wait
    // (guide rule #18: "memory" clobber alone does not order register-only
    // consumers; the sched_barrier immediately after is the fence).
    asm volatile("s_waitcnt vmcnt(0)" ::: "memory");
    __builtin_amdgcn_sched_barrier(0);

    float Zs[4] = {0,0,0,0}, Zt[4] = {0,0,0,0};
    float At[4] = {0,0,0,0}, As[4] = {0,0,0,0};
#pragma unroll
    for (int c = 0; c < NCLS; ++c) {
        float s[4] = {sv[c].x, sv[c].y, sv[c].z, sv[c].w};
        float t[4] = {tv[c].x, tv[c].y, tv[c].z, tv[c].w};
#pragma unroll
        for (int v = 0; v < 4; ++v) {
            float et = __expf(t[v]);
            Zt[v] += et;
            At[v] = fmaf(et, t[v], At[v]);
            As[v] = fmaf(et, s[v], As[v]);
            Zs[v] += __expf(s[v]);
        }
    }

    int cls[4] = {g.x, g.y, g.z, g.w};
#pragma unroll
    for (int v = 0; v < 4; ++v) {
        // kl = sum_c q(logq - logp) = (At - As)/Zt - log(Zt) + log(Zs)
        float kl = (At[v] - As[v]) / Zt[v] - __logf(Zt[v]) + __logf(Zs[v]);
        int c = min(max(cls[v], 0), NCLS - 1);
        atomicAdd(&lsum[b * NCLS + c], kl);
        atomicAdd(&lcnt[b * NCLS + c], 1);
    }

    __syncthreads();
    // 64-way-spread global accumulation: per-line atomic chain = 1728/64 = 27.
    if (threadIdx.x < NUM_BINS) {
        const int slot = blockIdx.x & (KSPREAD - 1);
        atomicAdd(&fsum[threadIdx.x * KSPREAD + slot], lsum[threadIdx.x]);
        atomicAdd(&fcnt[threadIdx.x * KSPREAD + slot], lcnt[threadIdx.x]);
    }
}

__global__ void kd12_final(const float* __restrict__ fsum,
                           const int* __restrict__ fcnt,
                           float* __restrict__ out) {
    __shared__ float terms[64];
    const int t = threadIdx.x;
    float term = 0.0f;
    if (t < NUM_BINS) {
        const float4* fp = reinterpret_cast<const float4*>(fsum + t * KSPREAD);
        const int4* cp = reinterpret_cast<const int4*>(fcnt + t * KSPREAD);
        float s = 0.0f; int n = 0;
#pragma unroll
        for (int i = 0; i < KSPREAD / 4; ++i) {   // fully unrolled: 32 indep loads
            float4 v = fp[i]; s += (v.x + v.y) + (v.z + v.w);
            int4 c = cp[i];   n += (c.x + c.y) + (c.z + c.w);
        }
        const int cls = t % NCLS;   // bin = b*NCLS + cls
        if (cls != 0 && n > 0) term = s / ((float)NCLS * (float)n);
    }
    terms[t] = term;
    __syncthreads();
    if (t == 0) {
        float loss = 0.0f;
#pragma unroll
        for (int i = 0; i < 64; ++i) loss += terms[i];
        out[0] = loss;   // TAU^2 = 1, LOSS_WEIGHT = 1
    }
}

extern "C" void kernel_launch(void* const* d_in, const int* in_sizes, int n_in,
                              void* d_out, int out_size, void* d_ws, size_t ws_size,
                              hipStream_t stream) {
    const float* S = (const float*)d_in[0];
    const float* T = (const float*)d_in[1];
    const int* gt = (const int*)d_in[2];
    float* out = (float*)d_out;

    float* fsum = (float*)d_ws;
    int* fcnt = (int*)((char*)d_ws + NUM_BINS * KSPREAD * sizeof(float));

    const int totalVox = in_sizes[2];       // 1,769,472 = 1728 * 1024
    const int N = totalVox / BATCH;         // 884,736 (divisible by 1024)

    const int block = 256;
    const int grid = totalVox / (block * 4);  // 1728 blocks, 4 voxels/thread

    kd12_zero<<<(NUM_BINS * KSPREAD) / 256, 256, 0, stream>>>(fsum, fcnt);  // 7 blocks
    kd12_kl<<<grid, block, 0, stream>>>(S, T, gt, fsum, fcnt, N);
    kd12_final<<<1, 64, 0, stream>>>(fsum, fcnt, out);
}

// Round 13
// 44.215 us; speedup vs baseline: 2.1459x; 1.0005x over previous
//
#include <hip/hip_runtime.h>
#include <stdint.h>

#define NCLS 14
#define BATCH 2
#define NUM_BINS (BATCH * NCLS)   // 28
#define KSPREAD 64                // per-bin atomic spread factor

// d_ws layout: float fsum[NUM_BINS*KSPREAD] | int fcnt[NUM_BINS*KSPREAD]

__global__ void kd13_zero(float* __restrict__ fsum, int* __restrict__ fcnt) {
    int i = blockIdx.x * blockDim.x + threadIdx.x;   // grid covers 1792 exactly
    fsum[i] = 0.0f;
    fcnt[i] = 0;
}

__global__ __launch_bounds__(256) void kd13_kl(
        const float* __restrict__ S, const float* __restrict__ T,
        const int* __restrict__ gt,
        float* __restrict__ fsum, int* __restrict__ fcnt,
        int N /* voxels per batch image */) {
    // Per-wave sum bins (4x contention cut); counts via ballot (no atomics).
    __shared__ float lsum[4][16];
    __shared__ int lcnt[4][16];
    const int tid = threadIdx.x;
    const int wave = tid >> 6, lane = tid & 63;
    if (tid < 64) { lsum[tid >> 4][tid & 15] = 0.0f; lcnt[tid >> 4][tid & 15] = 0; }
    __syncthreads();

    // b from blockIdx only -> block-uniform -> SGPR channel bases (saddr form).
    const int b = ((unsigned)blockIdx.x * 1024u >= (unsigned)N) ? 1 : 0;
    const int gid = blockIdx.x * blockDim.x + tid;
    const int v0 = gid * 4;                       // 4 voxels per thread
    const int n = v0 - b * N;

    const float* Sb = S + (size_t)b * NCLS * N;   // uniform (SGPR pair)
    const float* Tb = T + (size_t)b * NCLS * N;   // uniform (SGPR pair)
    const uint32_t voff = (uint32_t)n * 4u;       // per-lane byte offset

    float4 sv[NCLS], tv[NCLS];

    // ---- Force 28 independent dwordx4 loads in flight (28 KB/wave). ----
    asm volatile(
        "global_load_dwordx4 %[d0], %[vo], %[p0]\n\t"
        "global_load_dwordx4 %[d1], %[vo], %[p1]\n\t"
        "global_load_dwordx4 %[d2], %[vo], %[p2]\n\t"
        "global_load_dwordx4 %[d3], %[vo], %[p3]\n\t"
        "global_load_dwordx4 %[d4], %[vo], %[p4]\n\t"
        "global_load_dwordx4 %[d5], %[vo], %[p5]\n\t"
        "global_load_dwordx4 %[d6], %[vo], %[p6]\n\t"
        : [d0]"=v"(sv[0]), [d1]"=v"(sv[1]), [d2]"=v"(sv[2]), [d3]"=v"(sv[3]),
          [d4]"=v"(sv[4]), [d5]"=v"(sv[5]), [d6]"=v"(sv[6])
        : [vo]"v"(voff),
          [p0]"s"(Sb + 0*(size_t)N), [p1]"s"(Sb + 1*(size_t)N),
          [p2]"s"(Sb + 2*(size_t)N), [p3]"s"(Sb + 3*(size_t)N),
          [p4]"s"(Sb + 4*(size_t)N), [p5]"s"(Sb + 5*(size_t)N),
          [p6]"s"(Sb + 6*(size_t)N));
    asm volatile(
        "global_load_dwordx4 %[d0], %[vo], %[p0]\n\t"
        "global_load_dwordx4 %[d1], %[vo], %[p1]\n\t"
        "global_load_dwordx4 %[d2], %[vo], %[p2]\n\t"
        "global_load_dwordx4 %[d3], %[vo], %[p3]\n\t"
        "global_load_dwordx4 %[d4], %[vo], %[p4]\n\t"
        "global_load_dwordx4 %[d5], %[vo], %[p5]\n\t"
        "global_load_dwordx4 %[d6], %[vo], %[p6]\n\t"
        : [d0]"=v"(sv[7]), [d1]"=v"(sv[8]), [d2]"=v"(sv[9]), [d3]"=v"(sv[10]),
          [d4]"=v"(sv[11]), [d5]"=v"(sv[12]), [d6]"=v"(sv[13])
        : [vo]"v"(voff),
          [p0]"s"(Sb + 7*(size_t)N), [p1]"s"(Sb + 8*(size_t)N),
          [p2]"s"(Sb + 9*(size_t)N), [p3]"s"(Sb + 10*(size_t)N),
          [p4]"s"(Sb + 11*(size_t)N), [p5]"s"(Sb + 12*(size_t)N),
          [p6]"s"(Sb + 13*(size_t)N));
    asm volatile(
        "global_load_dwordx4 %[d0], %[vo], %[p0]\n\t"
        "global_load_dwordx4 %[d1], %[vo], %[p1]\n\t"
        "global_load_dwordx4 %[d2], %[vo], %[p2]\n\t"
        "global_load_dwordx4 %[d3], %[vo], %[p3]\n\t"
        "global_load_dwordx4 %[d4], %[vo], %[p4]\n\t"
        "global_load_dwordx4 %[d5], %[vo], %[p5]\n\t"
        "global_load_dwordx4 %[d6], %[vo], %[p6]\n\t"
        : [d0]"=v"(tv[0]), [d1]"=v"(tv[1]), [d2]"=v"(tv[2]), [d3]"=v"(tv[3]),
          [d4]"=v"(tv[4]), [d5]"=v"(tv[5]), [d6]"=v"(tv[6])
        : [vo]"v"(voff),
          [p0]"s"(Tb + 0*(size_t)N), [p1]"s"(Tb + 1*(size_t)N),
          [p2]"s"(Tb + 2*(size_t)N), [p3]"s"(Tb + 3*(size_t)N),
          [p4]"s"(Tb + 4*(size_t)N), [p5]"s"(Tb + 5*(size_t)N),
          [p6]"s"(Tb + 6*(size_t)N));
    asm volatile(
        "global_load_dwordx4 %[d0], %[vo], %[p0]\n\t"
        "global_load_dwordx4 %[d1], %[vo], %[p1]\n\t"
        "global_load_dwordx4 %[d2], %[vo], %[p2]\n\t"
        "global_load_dwordx4 %[d3], %[vo], %[p3]\n\t"
        "global_load_dwordx4 %[d4], %[vo], %[p4]\n\t"
        "global_load_dwordx4 %[d5], %[vo], %[p5]\n\t"
        "global_load_dwordx4 %[d6], %[vo], %[p6]\n\t"
        : [d0]"=v"(tv[7]), [d1]"=v"(tv[8]), [d2]"=v"(tv[9]), [d3]"=v"(tv[10]),
          [d4]"=v"(tv[11]), [d5]"=v"(tv[12]), [d6]"=v"(tv[13])
        : [vo]"v"(voff),
          [p0]"s"(Tb + 7*(size_t)N), [p1]"s"(Tb + 8*(size_t)N),
          [p2]"s"(Tb + 9*(size_t)N), [p3]"s"(Tb + 10*(size_t)N),
          [p4]"s"(Tb + 11*(size_t)N), [p5]"s"(Tb + 12*(size_t)N),
          [p6]"s"(Tb + 13*(size_t)N));

    int4 g = *reinterpret_cast<const int4*>(gt + v0);

    asm volatile("s_waitcnt vmcnt(0)" ::: "memory");
    __builtin_amdgcn_sched_barrier(0);

    float Zs[4] = {0,0,0,0}, Zt[4] = {0,0,0,0};
    float At[4] = {0,0,0,0}, As[4] = {0,0,0,0};
#pragma unroll
    for (int c = 0; c < NCLS; ++c) {
        float s[4] = {sv[c].x, sv[c].y, sv[c].z, sv[c].w};
        float t[4] = {tv[c].x, tv[c].y, tv[c].z, tv[c].w};
#pragma unroll
        for (int v = 0; v < 4; ++v) {
            float et = __expf(t[v]);
            Zt[v] += et;
            At[v] = fmaf(et, t[v], At[v]);
            As[v] = fmaf(et, s[v], As[v]);
            Zs[v] += __expf(s[v]);
        }
    }

    int cls[4];
    cls[0] = min(max(g.x, 0), NCLS - 1);
    cls[1] = min(max(g.y, 0), NCLS - 1);
    cls[2] = min(max(g.z, 0), NCLS - 1);
    cls[3] = min(max(g.w, 0), NCLS - 1);

    // Sums: per-wave LDS atomics (4x less same-address contention).
#pragma unroll
    for (int v = 0; v < 4; ++v) {
        float kl = (At[v] - As[v]) / Zt[v] - __logf(Zt[v]) + __logf(Zs[v]);
        atomicAdd(&lsum[wave][cls[v]], kl);
    }
    // Counts: ballot + popcount, no atomics at all.
#pragma unroll
    for (int c = 0; c < NCLS; ++c) {
        int nvc = 0;
#pragma unroll
        for (int v = 0; v < 4; ++v)
            nvc += __popcll(__ballot(cls[v] == c));
        if (lane == 0) lcnt[wave][c] = nvc;
    }

    __syncthreads();
    // Only 14 bins are live per block (b is uniform): 28 global atomics, not 56.
    if (tid < NCLS) {
        float s = lsum[0][tid] + lsum[1][tid] + lsum[2][tid] + lsum[3][tid];
        int nn = lcnt[0][tid] + lcnt[1][tid] + lcnt[2][tid] + lcnt[3][tid];
        const int slot = blockIdx.x & (KSPREAD - 1);
        const int bin = b * NCLS + tid;
        atomicAdd(&fsum[bin * KSPREAD + slot], s);
        atomicAdd(&fcnt[bin * KSPREAD + slot], nn);
    }
}

__global__ void kd13_final(const float* __restrict__ fsum,
                           const int* __restrict__ fcnt,
                           float* __restrict__ out) {
    __shared__ float terms[64];
    const int t = threadIdx.x;
    float term = 0.0f;
    if (t < NUM_BINS) {
        const float4* fp = reinterpret_cast<const float4*>(fsum + t * KSPREAD);
        const int4* cp = reinterpret_cast<const int4*>(fcnt + t * KSPREAD);
        float s = 0.0f; int n = 0;
#pragma unroll
        for (int i = 0; i < KSPREAD / 4; ++i) {   // fully unrolled: 32 indep loads
            float4 v = fp[i]; s += (v.x + v.y) + (v.z + v.w);
            int4 c = cp[i];   n += (c.x + c.y) + (c.z + c.w);
        }
        const int cls = t % NCLS;   // bin = b*NCLS + cls
        if (cls != 0 && n > 0) term = s / ((float)NCLS * (float)n);
    }
    terms[t] = term;
    __syncthreads();
    if (t == 0) {
        float loss = 0.0f;
#pragma unroll
        for (int i = 0; i < 64; ++i) loss += terms[i];
        out[0] = loss;   // TAU^2 = 1, LOSS_WEIGHT = 1
    }
}

extern "C" void kernel_launch(void* const* d_in, const int* in_sizes, int n_in,
                              void* d_out, int out_size, void* d_ws, size_t ws_size,
                              hipStream_t stream) {
    const float* S = (const float*)d_in[0];
    const float* T = (const float*)d_in[1];
    const int* gt = (const int*)d_in[2];
    float* out = (float*)d_out;

    float* fsum = (float*)d_ws;
    int* fcnt = (int*)((char*)d_ws + NUM_BINS * KSPREAD * sizeof(float));

    const int totalVox = in_sizes[2];       // 1,769,472 = 1728 * 1024
    const int N = totalVox / BATCH;         // 884,736 (divisible by 1024)

    const int block = 256;
    const int grid = totalVox / (block * 4);  // 1728 blocks, 4 voxels/thread

    kd13_zero<<<(NUM_BINS * KSPREAD) / 256, 256, 0, stream>>>(fsum, fcnt);  // 7 blocks
    kd13_kl<<<grid, block, 0, stream>>>(S, T, gt, fsum, fcnt, N);
    kd13_final<<<1, 64, 0, stream>>>(fsum, fcnt, out);
}